// Round 4
// baseline (396.426 us; speedup 1.0000x reference)
//
#include <hip/hip_runtime.h>

#define HW 64
#define NPIX 4096
#define NB 128
#define NA 10
#define HCH 150
#define VS 68      // LDS row stride (64 + 2 ring + pad)
#define VROWS 66

// composed-weight layout in ws (222 floats):
//   [0..49]    K5[2][5][5]
//   [50]       C
//   [51..212]  M[9][2][9]
//   [213..221] Bd[9]
#define N_PRE 222

// ---------------------------------------------------------------------------
// Kernel 0: fold the 2->150->1 conv pair into composed 5x5 kernel + border
// correction kernels. One block (1 wave) per output element; channel loop
// split across the 64 lanes + shuffle reduction.
// ---------------------------------------------------------------------------
__global__ __launch_bounds__(64) void precompute_kernels(
        const float* __restrict__ Wh,   // [150][2][9]
        const float* __restrict__ bh,   // [150]
        const float* __restrict__ Wr,   // [150][9]
        float* __restrict__ kw) {       // [222]
    int o = blockIdx.x;      // 0..221
    int lane = threadIdx.x;  // 0..63
    float s = 0.f;
    if (o < 50) {
        // K5[ci][u][v] = sum_ch sum_{ky,kx} Wr[ch][ky][kx] * Wh[ch][ci][u-ky][v-kx]
        int ci = o / 25, uv = o % 25, u = uv / 5, v = uv % 5;
        for (int ch = lane; ch < HCH; ch += 64) {
            const float* wr = Wr + ch * 9;
            const float* wh = Wh + ch * 18 + ci * 9;
            for (int ky = 0; ky < 3; ++ky) {
                int ey = u - ky; if (ey < 0 || ey > 2) continue;
                for (int kx = 0; kx < 3; ++kx) {
                    int ex = v - kx; if (ex < 0 || ex > 2) continue;
                    s += wr[ky * 3 + kx] * wh[ey * 3 + ex];
                }
            }
        }
    } else if (o == 50) {
        // C = sum_ch bh[ch] * sum_t Wr[ch][t]
        for (int ch = lane; ch < HCH; ch += 64) {
            float wsum = 0.f;
            for (int t = 0; t < 9; ++t) wsum += Wr[ch * 9 + t];
            s += wsum * bh[ch];
        }
    } else if (o < 51 + 162) {
        // M[d][ci][e] = sum_ch Wr[ch][d] * Wh[ch][ci][e]
        int m = o - 51;
        int d = m / 18, rest = m % 18, ci = rest / 9, e = rest % 9;
        for (int ch = lane; ch < HCH; ch += 64)
            s += Wr[ch * 9 + d] * Wh[ch * 18 + ci * 9 + e];
    } else {
        // Bd[d] = sum_ch Wr[ch][d] * bh[ch]
        int d = o - 213;
        for (int ch = lane; ch < HCH; ch += 64)
            s += Wr[ch * 9 + d] * bh[ch];
    }
    #pragma unroll
    for (int off = 32; off > 0; off >>= 1) s += __shfl_down(s, off);
    if (lane == 0) kw[o] = s;
}

// ---------------------------------------------------------------------------
// Kernel 1 (fused): per image — compute r from obs via composed 5x5 conv
// (+ exact border corrections) straight into LDS, then the full value
// iteration with bitwise-exact early exit, then gather + FC.
// One block per image, 512 threads, 4x2 pixels/thread.
// amdgpu_waves_per_eu(2,2): pin allocator budget to 256 VGPRs so qr[8][10]
// and wv[10][9] stay register-resident (R3 spilled qr: 20 MB scratch writes).
// ---------------------------------------------------------------------------
__global__ __launch_bounds__(512) __attribute__((amdgpu_waves_per_eu(2, 2)))
void vi_fused(const float* __restrict__ obs,   // [128][2][64][64]
              const float* __restrict__ kw,    // [222] composed weights
              const float* __restrict__ Wi,    // w_i2q [10][9]
              const float* __restrict__ Wvq,   // w_v2q [10][9]
              const float* __restrict__ Wfc,   // [8][10]
              const int* __restrict__ s1, const int* __restrict__ s2,
              const int* __restrict__ kptr,
              float* __restrict__ out) {       // [128][8]
    __shared__ float buf0[VROWS * VS];    // r, then v buffer
    __shared__ float buf1[VROWS * VS];    // v buffer
    __shared__ float wil[90];
    __shared__ float wvl[90];
    __shared__ float kwl[N_PRE];
    __shared__ int chg[3];                // rotating convergence flags
    int tid = threadIdx.x;
    int b = blockIdx.x;

    for (int i = tid; i < VROWS * VS; i += 512) { buf0[i] = 0.f; buf1[i] = 0.f; }
    if (tid < 90)    { wil[tid] = Wi[tid]; wvl[tid] = Wvq[tid]; }
    if (tid < N_PRE) kwl[tid] = kw[tid];
    if (tid < 3)     chg[tid] = 0;
    __syncthreads();

    // thread owns a 4-row x 2-col patch
    int tx = tid & 31, ty = tid >> 5;
    int x0 = tx * 2, y0 = ty * 4;

    // ---- phase 1: r for my 8 pixels, straight into buf0 interior ----
    {
        const float* ob0 = obs + (size_t)b * 2 * NPIX;
        const float* ob1 = ob0 + NPIX;
        const float* K5 = kwl;
        const float  C  = kwl[50];
        const float* M  = kwl + 51;
        const float* Bd = kwl + 213;
        for (int py = 0; py < 4; ++py) {
            for (int px = 0; px < 2; ++px) {
                int y = y0 + py, x = x0 + px;
                float acc = C;
                #pragma unroll
                for (int u = 0; u < 5; ++u) {
                    int gy = y + u - 2;
                    if (gy < 0 || gy > 63) continue;
                    #pragma unroll
                    for (int v = 0; v < 5; ++v) {
                        int gx = x + v - 2;
                        if (gx < 0 || gx > 63) continue;
                        acc += K5[u * 5 + v] * ob0[gy * 64 + gx]
                             + K5[25 + u * 5 + v] * ob1[gy * 64 + gx];
                    }
                }
                if (y == 0 || y == 63 || x == 0 || x == 63) {
                    for (int d = 0; d < 9; ++d) {
                        int ny = y + d / 3 - 1, nx = x + d % 3 - 1;
                        if (ny >= 0 && ny <= 63 && nx >= 0 && nx <= 63) continue;
                        float corr = Bd[d];
                        for (int e = 0; e < 9; ++e) {
                            int oy = ny + e / 3 - 1, ox = nx + e % 3 - 1;
                            if (oy < 0 || oy > 63 || ox < 0 || ox > 63) continue;
                            corr += M[d * 18 + e]     * ob0[oy * 64 + ox]
                                  + M[d * 18 + 9 + e] * ob1[oy * 64 + ox];
                        }
                        acc -= corr;
                    }
                }
                buf0[(y + 1) * VS + (x + 1)] = acc;
            }
        }
    }
    __syncthreads();

    // ---- phase 2: qr = conv(r, Wi) (iteration-invariant), v0 -> buf1 ----
    float qr[8][NA];
    {
        float wt[NA][9];
        #pragma unroll
        for (int a = 0; a < NA; ++a)
            #pragma unroll
            for (int t = 0; t < 9; ++t) wt[a][t] = wil[a * 9 + t];
        float rn[6][4];
        #pragma unroll
        for (int r = 0; r < 6; ++r)
            #pragma unroll
            for (int c = 0; c < 4; ++c)
                rn[r][c] = buf0[(y0 + r) * VS + (x0 + c)];
        #pragma unroll
        for (int py = 0; py < 4; ++py) {
            #pragma unroll
            for (int px = 0; px < 2; ++px) {
                float vmax = -1e30f;
                #pragma unroll
                for (int a = 0; a < NA; ++a) {
                    float acc = 0.f;
                    #pragma unroll
                    for (int ky = 0; ky < 3; ++ky)
                        #pragma unroll
                        for (int kx = 0; kx < 3; ++kx)
                            acc += wt[a][ky * 3 + kx] * rn[py + ky][px + kx];
                    qr[py * 2 + px][a] = acc;
                    vmax = fmaxf(vmax, acc);
                }
                buf1[(y0 + py + 1) * VS + (x0 + px + 1)] = vmax;
            }
        }
    }

    // Wv into registers (shared across all 8 pixels, all iterations)
    float wv[NA][9];
    #pragma unroll
    for (int a = 0; a < NA; ++a)
        #pragma unroll
        for (int t = 0; t < 9; ++t) wv[a][t] = wvl[a * 9 + t];
    __syncthreads();
    // buf1 = v_cur; buf0 interior (r) is dead — fully overwritten in iter 0
    // before anyone reads it as v. Rings of both buffers stay 0.

    // ---- phase 3: VI loop, single barrier/iter, bitwise early exit ----
    // 3-slot flag protocol: slot p=it%3 is set (pre-barrier) and read
    // (post-barrier) in iter it; it is reset at the TOP of iter it+2, which
    // is after barrier(it+1) (all readers done) and before barrier(it+2)
    // (next setters at iter it+3 come later). Race-free, uniform exit.
    int K = kptr[0];
    float* cur = buf1;
    float* nxt = buf0;
    for (int it = 0; it < K; ++it) {
        chg[(it + 1) % 3] = 0;   // prepares slot for iter it+1 (see proof above)
        float vn[6][4];
        #pragma unroll
        for (int r = 0; r < 6; ++r)
            #pragma unroll
            for (int c = 0; c < 4; ++c)
                vn[r][c] = cur[(y0 + r) * VS + (x0 + c)];
        bool changed = false;
        #pragma unroll
        for (int py = 0; py < 4; ++py) {
            #pragma unroll
            for (int px = 0; px < 2; ++px) {
                float m = -1e30f;
                #pragma unroll
                for (int a = 0; a < NA; ++a) {
                    float acc = qr[py * 2 + px][a];
                    #pragma unroll
                    for (int ky = 0; ky < 3; ++ky)
                        #pragma unroll
                        for (int kx = 0; kx < 3; ++kx)
                            acc += wv[a][ky * 3 + kx] * vn[py + ky][px + kx];
                    m = fmaxf(m, acc);
                }
                nxt[(y0 + py + 1) * VS + (x0 + px + 1)] = m;
                changed |= (__float_as_int(m) != __float_as_int(vn[py + 1][px + 1]));
            }
        }
        if (changed) chg[it % 3] = 1;
        __syncthreads();
        if (chg[it % 3] == 0) break;   // v is a bitwise fixed point: all
                                       // remaining iterations are identity
        float* t = cur; cur = nxt; nxt = t;
    }

    // ---- phase 4: final q at attended pixel + FC (owner has qr in regs) ----
    int yy = s1[b], xx = s2[b];
    if (ty == (yy >> 2) && tx == (xx >> 1)) {
        int py = yy & 3, px = xx & 1;
        float q[NA];
        #pragma unroll
        for (int a = 0; a < NA; ++a) {
            float acc = qr[py * 2 + px][a];
            #pragma unroll
            for (int ky = 0; ky < 3; ++ky)
                #pragma unroll
                for (int kx = 0; kx < 3; ++kx)
                    acc += wv[a][ky * 3 + kx] * cur[(yy + ky) * VS + (xx + kx)];
            q[a] = acc;
        }
        for (int n = 0; n < 8; ++n) {
            float o = 0.f;
            for (int a = 0; a < NA; ++a) o += q[a] * Wfc[n * NA + a];
            out[b * 8 + n] = o;
        }
    }
}

// ---------------------------------------------------------------------------
extern "C" void kernel_launch(void* const* d_in, const int* in_sizes, int n_in,
                              void* d_out, int out_size, void* d_ws, size_t ws_size,
                              hipStream_t stream) {
    const int*   s1   = (const int*)d_in[0];
    const int*   s2   = (const int*)d_in[1];
    const float* obs  = (const float*)d_in[2];
    const int*   kptr = (const int*)d_in[3];
    const float* Wh   = (const float*)d_in[4];
    const float* bh   = (const float*)d_in[5];
    const float* Wr   = (const float*)d_in[6];
    const float* Wi   = (const float*)d_in[7];
    const float* Wvq  = (const float*)d_in[8];
    const float* Wfc  = (const float*)d_in[9];
    float* out = (float*)d_out;
    float* kw  = (float*)d_ws;   // 222 floats

    precompute_kernels<<<N_PRE, 64, 0, stream>>>(Wh, bh, Wr, kw);
    vi_fused<<<NB, 512, 0, stream>>>(obs, kw, Wi, Wvq, Wfc, s1, s2, kptr, out);
}

// Round 5
// 375.679 us; speedup vs baseline: 1.0552x; 1.0552x over previous
//
#include <hip/hip_runtime.h>

#define HW 64
#define NPIX 4096
#define NB 128
#define NA 10
#define HCH 150
#define VS 68      // LDS row stride (64 + 2 ring + pad)
#define VROWS 66

// composed-weight layout in ws (222 floats):
//   [0..49]    K5[2][5][5]
//   [50]       C
//   [51..212]  M[9][2][9]
//   [213..221] Bd[9]
#define N_PRE 222

// ---------------------------------------------------------------------------
// Kernel 0: fold the 2->150->1 conv pair into composed 5x5 kernel + border
// correction kernels. One block (1 wave) per output element; channel loop
// split across the 64 lanes + shuffle reduction.
// ---------------------------------------------------------------------------
__global__ __launch_bounds__(64) void precompute_kernels(
        const float* __restrict__ Wh,   // [150][2][9]
        const float* __restrict__ bh,   // [150]
        const float* __restrict__ Wr,   // [150][9]
        float* __restrict__ kw) {       // [222]
    int o = blockIdx.x;      // 0..221
    int lane = threadIdx.x;  // 0..63
    float s = 0.f;
    if (o < 50) {
        int ci = o / 25, uv = o % 25, u = uv / 5, v = uv % 5;
        for (int ch = lane; ch < HCH; ch += 64) {
            const float* wr = Wr + ch * 9;
            const float* wh = Wh + ch * 18 + ci * 9;
            for (int ky = 0; ky < 3; ++ky) {
                int ey = u - ky; if (ey < 0 || ey > 2) continue;
                for (int kx = 0; kx < 3; ++kx) {
                    int ex = v - kx; if (ex < 0 || ex > 2) continue;
                    s += wr[ky * 3 + kx] * wh[ey * 3 + ex];
                }
            }
        }
    } else if (o == 50) {
        for (int ch = lane; ch < HCH; ch += 64) {
            float wsum = 0.f;
            for (int t = 0; t < 9; ++t) wsum += Wr[ch * 9 + t];
            s += wsum * bh[ch];
        }
    } else if (o < 51 + 162) {
        int m = o - 51;
        int d = m / 18, rest = m % 18, ci = rest / 9, e = rest % 9;
        for (int ch = lane; ch < HCH; ch += 64)
            s += Wr[ch * 9 + d] * Wh[ch * 18 + ci * 9 + e];
    } else {
        int d = o - 213;
        for (int ch = lane; ch < HCH; ch += 64)
            s += Wr[ch * 9 + d] * bh[ch];
    }
    #pragma unroll
    for (int off = 32; off > 0; off >>= 1) s += __shfl_down(s, off);
    if (lane == 0) kw[o] = s;
}

// ---------------------------------------------------------------------------
// Kernel 1 (fused): per image — r from obs (composed 5x5 + exact border
// corrections) into LDS, then VI with the R1-proven loop shape (in-place v,
// two barriers, NO pointer swap, NO runtime register-array indexing) plus a
// bitwise-exact early exit, then gather + FC.
// One block per image, 512 threads, 4x2 pixels/thread, launch_bounds(512,2)
// — the R1 configuration that compiled spill-free at 120 VGPRs.
// ---------------------------------------------------------------------------
__global__ __launch_bounds__(512, 2) void vi_fused(
        const float* __restrict__ obs,   // [128][2][64][64]
        const float* __restrict__ kw,    // [222] composed weights
        const float* __restrict__ Wi,    // w_i2q [10][9]
        const float* __restrict__ Wvq,   // w_v2q [10][9]
        const float* __restrict__ Wfc,   // [8][10]
        const int* __restrict__ s1, const int* __restrict__ s2,
        const int* __restrict__ kptr,
        float* __restrict__ out) {       // [128][8]
    __shared__ float rlds[VROWS * VS];   // r (zero ring)
    __shared__ float vlds[VROWS * VS];   // v (zero ring), updated in place
    __shared__ float wil[90];
    __shared__ float wvl[90];
    __shared__ float kwl[N_PRE];
    __shared__ float qatt[NA];           // attended pixel's qr (phase-2 capture)
    __shared__ int   chg[2];             // ping-pong convergence flags
    int tid = threadIdx.x;
    int b = blockIdx.x;

    for (int i = tid; i < VROWS * VS; i += 512) { rlds[i] = 0.f; vlds[i] = 0.f; }
    if (tid < 90)    { wil[tid] = Wi[tid]; wvl[tid] = Wvq[tid]; }
    if (tid < N_PRE) kwl[tid] = kw[tid];
    if (tid < 2)     chg[tid] = 0;
    int yy = s1[b], xx = s2[b];
    __syncthreads();

    // thread owns a 4-row x 2-col patch
    int tx = tid & 31, ty = tid >> 5;
    int x0 = tx * 2, y0 = ty * 4;

    // ---- phase 1: r for my 8 pixels, straight into rlds interior ----
    {
        const float* ob0 = obs + (size_t)b * 2 * NPIX;
        const float* ob1 = ob0 + NPIX;
        const float* K5 = kwl;
        const float  C  = kwl[50];
        const float* M  = kwl + 51;
        const float* Bd = kwl + 213;
        for (int py = 0; py < 4; ++py) {
            for (int px = 0; px < 2; ++px) {
                int y = y0 + py, x = x0 + px;
                float acc = C;
                #pragma unroll
                for (int u = 0; u < 5; ++u) {
                    int gy = y + u - 2;
                    if (gy < 0 || gy > 63) continue;
                    #pragma unroll
                    for (int v = 0; v < 5; ++v) {
                        int gx = x + v - 2;
                        if (gx < 0 || gx > 63) continue;
                        acc += K5[u * 5 + v] * ob0[gy * 64 + gx]
                             + K5[25 + u * 5 + v] * ob1[gy * 64 + gx];
                    }
                }
                if (y == 0 || y == 63 || x == 0 || x == 63) {
                    for (int d = 0; d < 9; ++d) {
                        int ny = y + d / 3 - 1, nx = x + d % 3 - 1;
                        if (ny >= 0 && ny <= 63 && nx >= 0 && nx <= 63) continue;
                        float corr = Bd[d];
                        for (int e = 0; e < 9; ++e) {
                            int oy = ny + e / 3 - 1, ox = nx + e % 3 - 1;
                            if (oy < 0 || oy > 63 || ox < 0 || ox > 63) continue;
                            corr += M[d * 18 + e]     * ob0[oy * 64 + ox]
                                  + M[d * 18 + 9 + e] * ob1[oy * 64 + ox];
                        }
                        acc -= corr;
                    }
                }
                rlds[(y + 1) * VS + (x + 1)] = acc;
            }
        }
    }
    __syncthreads();

    // ---- phase 2: qr = conv(r, Wi) (iteration-invariant); v0 -> vlds ----
    // R1 style: wil read straight from LDS (one-time cost). The attended
    // pixel's qr row is captured into qatt with COMPILE-TIME indexing only.
    float qr[8][NA];
    #pragma unroll
    for (int py = 0; py < 4; ++py) {
        #pragma unroll
        for (int px = 0; px < 2; ++px) {
            int y = y0 + py, x = x0 + px;
            float rn[9];
            #pragma unroll
            for (int t = 0; t < 9; ++t)
                rn[t] = rlds[(y + t / 3) * VS + (x + t % 3)];
            bool own = (y == yy) && (x == xx);
            float vmax = -1e30f;
            #pragma unroll
            for (int a = 0; a < NA; ++a) {
                float acc = 0.f;
                #pragma unroll
                for (int t = 0; t < 9; ++t) acc += wil[a * 9 + t] * rn[t];
                qr[py * 2 + px][a] = acc;
                if (own) qatt[a] = acc;
                vmax = fmaxf(vmax, acc);
            }
            vlds[(y + 1) * VS + (x + 1)] = vmax;
        }
    }

    // Wv into registers (R1 pattern — compiler picks reg/LDS mix)
    float wv[NA][9];
    #pragma unroll
    for (int a = 0; a < NA; ++a)
        #pragma unroll
        for (int t = 0; t < 9; ++t) wv[a][t] = wvl[a * 9 + t];
    __syncthreads();

    // ---- phase 3: VI loop — in-place v, two barriers, exact early exit ----
    int K = kptr[0];
    for (int it = 0; it < K; ++it) {
        float vn[6][4];
        #pragma unroll
        for (int r = 0; r < 6; ++r)
            #pragma unroll
            for (int c = 0; c < 4; ++c)
                vn[r][c] = vlds[(y0 + r) * VS + (x0 + c)];
        float nv[8];
        bool changed = false;
        #pragma unroll
        for (int py = 0; py < 4; ++py) {
            #pragma unroll
            for (int px = 0; px < 2; ++px) {
                float m = -1e30f;
                #pragma unroll
                for (int a = 0; a < NA; ++a) {
                    float acc = qr[py * 2 + px][a];
                    #pragma unroll
                    for (int ky = 0; ky < 3; ++ky)
                        #pragma unroll
                        for (int kx = 0; kx < 3; ++kx)
                            acc += wv[a][ky * 3 + kx] * vn[py + ky][px + kx];
                    m = fmaxf(m, acc);
                }
                nv[py * 2 + px] = m;
                changed |= (__float_as_int(m) != __float_as_int(vn[py + 1][px + 1]));
            }
        }
        __syncthreads();   // B1: all reads of v_it done
        #pragma unroll
        for (int py = 0; py < 4; ++py)
            #pragma unroll
            for (int px = 0; px < 2; ++px)
                vlds[(y0 + py + 1) * VS + (x0 + px + 1)] = nv[py * 2 + px];
        chg[(it + 1) & 1] = 0;          // prep next slot (readers of this slot
                                        // are past B2(it+1) > this write; and
                                        // B1(it+1) orders it before their "=1")
        if (changed) chg[it & 1] = 1;   // benign same-value race
        __syncthreads();   // B2: v_{it+1} + flags visible
        if (chg[it & 1] == 0) break;    // bitwise fixed point: remaining
                                        // iterations are exact identities
    }

    // ---- phase 4: final q at attended pixel + FC (all-LDS, no reg indexing) ----
    if (tid == 0) {
        float q[NA];
        #pragma unroll
        for (int a = 0; a < NA; ++a) {
            float acc = qatt[a];
            #pragma unroll
            for (int ky = 0; ky < 3; ++ky)
                #pragma unroll
                for (int kx = 0; kx < 3; ++kx)
                    acc += wvl[a * 9 + ky * 3 + kx] * vlds[(yy + ky) * VS + (xx + kx)];
            q[a] = acc;
        }
        for (int n = 0; n < 8; ++n) {
            float o = 0.f;
            for (int a = 0; a < NA; ++a) o += q[a] * Wfc[n * NA + a];
            out[b * 8 + n] = o;
        }
    }
}

// ---------------------------------------------------------------------------
extern "C" void kernel_launch(void* const* d_in, const int* in_sizes, int n_in,
                              void* d_out, int out_size, void* d_ws, size_t ws_size,
                              hipStream_t stream) {
    const int*   s1   = (const int*)d_in[0];
    const int*   s2   = (const int*)d_in[1];
    const float* obs  = (const float*)d_in[2];
    const int*   kptr = (const int*)d_in[3];
    const float* Wh   = (const float*)d_in[4];
    const float* bh   = (const float*)d_in[5];
    const float* Wr   = (const float*)d_in[6];
    const float* Wi   = (const float*)d_in[7];
    const float* Wvq  = (const float*)d_in[8];
    const float* Wfc  = (const float*)d_in[9];
    float* out = (float*)d_out;
    float* kw  = (float*)d_ws;   // 222 floats

    precompute_kernels<<<N_PRE, 64, 0, stream>>>(Wh, bh, Wr, kw);
    vi_fused<<<NB, 512, 0, stream>>>(obs, kw, Wi, Wvq, Wfc, s1, s2, kptr, out);
}

// Round 6
// 328.457 us; speedup vs baseline: 1.2069x; 1.1438x over previous
//
#include <hip/hip_runtime.h>

#define HW 64
#define NPIX 4096
#define NB 128
#define NA 10
#define HCH 150
#define VS 68      // LDS row stride (64 + 2 ring + pad)
#define VROWS 66

typedef float f2 __attribute__((ext_vector_type(2)));

// workspace float offsets
#define R_OFF 0
#define R_SZ (NB * NPIX)        // 524288 floats
#define K5_OFF (R_SZ)           // 50 floats: K5[2][5][5]
#define C_OFF (K5_OFF + 50)     // 1
#define M_OFF (C_OFF + 1)       // 162: M[9][2][9]
#define BD_OFF (M_OFF + 162)    // 9
#define N_PRE 222

// ---------------------------------------------------------------------------
// Kernel 0: fold the 2->150->1 conv pair into composed 5x5 kernel + border
// correction kernels. One block (1 wave) per output element.
// ---------------------------------------------------------------------------
__global__ __launch_bounds__(64) void precompute_kernels(
        const float* __restrict__ Wh,   // [150][2][9]
        const float* __restrict__ bh,   // [150]
        const float* __restrict__ Wr,   // [150][9]
        float* __restrict__ ws) {
    int o = blockIdx.x;      // 0..221
    int lane = threadIdx.x;  // 0..63
    float s = 0.f;
    if (o < 50) {
        int ci = o / 25, uv = o % 25, u = uv / 5, v = uv % 5;
        for (int ch = lane; ch < HCH; ch += 64) {
            const float* wr = Wr + ch * 9;
            const float* wh = Wh + ch * 18 + ci * 9;
            for (int ky = 0; ky < 3; ++ky) {
                int ey = u - ky; if (ey < 0 || ey > 2) continue;
                for (int kx = 0; kx < 3; ++kx) {
                    int ex = v - kx; if (ex < 0 || ex > 2) continue;
                    s += wr[ky * 3 + kx] * wh[ey * 3 + ex];
                }
            }
        }
    } else if (o == 50) {
        for (int ch = lane; ch < HCH; ch += 64) {
            float wsum = 0.f;
            for (int t = 0; t < 9; ++t) wsum += Wr[ch * 9 + t];
            s += wsum * bh[ch];
        }
    } else if (o < 51 + 162) {
        int m = o - 51;
        int d = m / 18, rest = m % 18, ci = rest / 9, e = rest % 9;
        for (int ch = lane; ch < HCH; ch += 64)
            s += Wr[ch * 9 + d] * Wh[ch * 18 + ci * 9 + e];
    } else {
        int d = o - 213;
        for (int ch = lane; ch < HCH; ch += 64)
            s += Wr[ch * 9 + d] * bh[ch];
    }
    #pragma unroll
    for (int off = 32; off > 0; off >>= 1) s += __shfl_down(s, off);
    if (lane == 0) ws[K5_OFF + o] = s;
}

// ---------------------------------------------------------------------------
// Kernel 1: r = composed 5x5 conv on obs (+C), with exact border corrections.
// One thread per output pixel. (R1-proven version, unchanged.)
// ---------------------------------------------------------------------------
__global__ __launch_bounds__(256) void compute_r(
        const float* __restrict__ obs,    // [128][2][64][64]
        const float* __restrict__ wsro,   // K5/C/M/Bd region (ws base)
        float* __restrict__ rg) {         // [128][64][64]
    int idx = blockIdx.x * 256 + threadIdx.x;   // 0 .. 524287
    int b = idx >> 12, p = idx & 4095, y = p >> 6, x = p & 63;
    const float* ob0 = obs + (size_t)b * 2 * NPIX;
    const float* ob1 = ob0 + NPIX;
    const float* K5 = wsro + K5_OFF;
    float acc = wsro[C_OFF];
    #pragma unroll
    for (int u = 0; u < 5; ++u) {
        int gy = y + u - 2;
        if (gy < 0 || gy > 63) continue;
        #pragma unroll
        for (int v = 0; v < 5; ++v) {
            int gx = x + v - 2;
            if (gx < 0 || gx > 63) continue;
            acc += K5[u * 5 + v] * ob0[gy * 64 + gx]
                 + K5[25 + u * 5 + v] * ob1[gy * 64 + gx];
        }
    }
    if (y == 0 || y == 63 || x == 0 || x == 63) {
        const float* M  = wsro + M_OFF;
        const float* Bd = wsro + BD_OFF;
        for (int d = 0; d < 9; ++d) {
            int ny = y + d / 3 - 1, nx = x + d % 3 - 1;
            if (ny >= 0 && ny <= 63 && nx >= 0 && nx <= 63) continue;
            float corr = Bd[d];
            for (int e = 0; e < 9; ++e) {
                int oy = ny + e / 3 - 1, ox = nx + e % 3 - 1;
                if (oy < 0 || oy > 63 || ox < 0 || ox > 63) continue;
                corr += M[d * 18 + e]     * ob0[oy * 64 + ox]
                      + M[d * 18 + 9 + e] * ob1[oy * 64 + ox];
            }
            acc -= corr;
        }
    }
    rg[idx] = acc;
}

// ---------------------------------------------------------------------------
// Kernel 2: value iteration — R1-proven structure (one block/image, 512 thr,
// 4x2 px/thread, in-place v, two barriers, tid0 tail from LDS) with two
// pressure-neutral changes:
//   (a) packed-fp32 inner loop (pixel pairs share wv scalars -> v_pk_fma_f32)
//   (b) bitwise-exact early exit (2-slot flag; once v_{t+1}==v_t bitwise, all
//       remaining iterations are exact identities)
// ---------------------------------------------------------------------------
__global__ __launch_bounds__(512, 2) void vi_kernel(
        const float* __restrict__ rg,     // [128][64][64]
        const float* __restrict__ Wi,     // w_i2q [10][9]
        const float* __restrict__ Wvq,    // w_v2q [10][9]
        const float* __restrict__ Wfc,    // [8][10]
        const int* __restrict__ s1, const int* __restrict__ s2,
        const int* __restrict__ kptr,
        float* __restrict__ out) {        // [128][8]
    __shared__ float rlds[VROWS * VS];
    __shared__ float vlds[VROWS * VS];
    __shared__ float wil[90];
    __shared__ float wvl[90];
    __shared__ int   chg[2];
    int tid = threadIdx.x;
    int b = blockIdx.x;

    for (int i = tid; i < VROWS * VS; i += 512) { rlds[i] = 0.f; vlds[i] = 0.f; }
    if (tid < 90) { wil[tid] = Wi[tid]; wvl[tid] = Wvq[tid]; }
    if (tid < 2)  chg[tid] = 0;
    __syncthreads();

    const float* rb = rg + (size_t)b * NPIX;
    for (int i = tid; i < NPIX; i += 512) {
        int y = i >> 6, x = i & 63;
        rlds[(y + 1) * VS + (x + 1)] = rb[i];
    }
    __syncthreads();

    // thread owns a 4-row x 2-col patch
    int tx = tid & 31, ty = tid >> 5;
    int x0 = tx * 2, y0 = ty * 4;

    // qr2[py][a] = conv(r, Wi) at the pixel pair (px=0 -> .x, px=1 -> .y)
    f2 qr2[4][NA];
    #pragma unroll
    for (int py = 0; py < 4; ++py) {
        #pragma unroll
        for (int px = 0; px < 2; ++px) {
            int y = y0 + py, x = x0 + px;
            float rn[9];
            #pragma unroll
            for (int t = 0; t < 9; ++t)
                rn[t] = rlds[(y + t / 3) * VS + (x + t % 3)];
            float vmax = -1e30f;
            #pragma unroll
            for (int a = 0; a < NA; ++a) {
                float acc = 0.f;
                #pragma unroll
                for (int t = 0; t < 9; ++t) acc += wil[a * 9 + t] * rn[t];
                qr2[py][a][px] = acc;
                vmax = fmaxf(vmax, acc);
            }
            vlds[(y + 1) * VS + (x + 1)] = vmax;
        }
    }

    // Wv into registers (R1 pattern — compiler picks reg/LDS mix)
    float wv[NA][9];
    #pragma unroll
    for (int a = 0; a < NA; ++a)
        #pragma unroll
        for (int t = 0; t < 9; ++t) wv[a][t] = wvl[a * 9 + t];
    __syncthreads();

    int K = kptr[0];
    for (int it = 0; it < K; ++it) {
        float vn[6][4];
        #pragma unroll
        for (int r = 0; r < 6; ++r)
            #pragma unroll
            for (int c = 0; c < 4; ++c)
                vn[r][c] = vlds[(y0 + r) * VS + (x0 + c)];
        f2 nv[4];
        bool changed = false;
        #pragma unroll
        for (int py = 0; py < 4; ++py) {
            f2 m = { -1e30f, -1e30f };
            #pragma unroll
            for (int a = 0; a < NA; ++a) {
                f2 acc = qr2[py][a];
                #pragma unroll
                for (int ky = 0; ky < 3; ++ky) {
                    f2 p0 = { vn[py + ky][0], vn[py + ky][1] };
                    f2 p1 = { vn[py + ky][1], vn[py + ky][2] };
                    f2 p2 = { vn[py + ky][2], vn[py + ky][3] };
                    acc += wv[a][ky * 3 + 0] * p0;
                    acc += wv[a][ky * 3 + 1] * p1;
                    acc += wv[a][ky * 3 + 2] * p2;
                }
                m.x = fmaxf(m.x, acc.x);
                m.y = fmaxf(m.y, acc.y);
            }
            nv[py] = m;
            changed |= (__float_as_int(m.x) != __float_as_int(vn[py + 1][1]));
            changed |= (__float_as_int(m.y) != __float_as_int(vn[py + 1][2]));
        }
        __syncthreads();   // B1: all reads of v_it done
        #pragma unroll
        for (int py = 0; py < 4; ++py) {
            vlds[(y0 + py + 1) * VS + (x0 + 1)] = nv[py].x;
            vlds[(y0 + py + 1) * VS + (x0 + 2)] = nv[py].y;
        }
        chg[(it + 1) & 1] = 0;          // prep next slot: readers of it+1 are
                                        // past B2(it+1); setters past B1(it+1)
        if (changed) chg[it & 1] = 1;   // benign same-value race
        __syncthreads();   // B2: v_{it+1} + flags visible
        if (chg[it & 1] == 0) break;    // bitwise fixed point reached
    }

    // final q at attended pixel + FC (R1 tail: all from LDS, tid 0)
    if (tid == 0) {
        int yy = s1[b], xx = s2[b];
        float q[NA];
        #pragma unroll
        for (int a = 0; a < NA; ++a) {
            float acc = 0.f;
            for (int t = 0; t < 9; ++t) {
                int ly = yy + t / 3, lx = xx + t % 3;
                acc += wil[a * 9 + t] * rlds[ly * VS + lx]
                     + wvl[a * 9 + t] * vlds[ly * VS + lx];
            }
            q[a] = acc;
        }
        for (int n = 0; n < 8; ++n) {
            float o = 0.f;
            for (int a = 0; a < NA; ++a) o += q[a] * Wfc[n * NA + a];
            out[b * 8 + n] = o;
        }
    }
}

// ---------------------------------------------------------------------------
extern "C" void kernel_launch(void* const* d_in, const int* in_sizes, int n_in,
                              void* d_out, int out_size, void* d_ws, size_t ws_size,
                              hipStream_t stream) {
    const int*   s1   = (const int*)d_in[0];
    const int*   s2   = (const int*)d_in[1];
    const float* obs  = (const float*)d_in[2];
    const int*   kptr = (const int*)d_in[3];
    const float* Wh   = (const float*)d_in[4];
    const float* bh   = (const float*)d_in[5];
    const float* Wr   = (const float*)d_in[6];
    const float* Wi   = (const float*)d_in[7];
    const float* Wvq  = (const float*)d_in[8];
    const float* Wfc  = (const float*)d_in[9];
    float* out = (float*)d_out;
    float* ws  = (float*)d_ws;

    precompute_kernels<<<N_PRE, 64, 0, stream>>>(Wh, bh, Wr, ws);
    compute_r<<<2048, 256, 0, stream>>>(obs, ws, ws + R_OFF);
    vi_kernel<<<NB, 512, 0, stream>>>(ws + R_OFF, Wi, Wvq, Wfc, s1, s2, kptr, out);
}

// Round 7
// 150.749 us; speedup vs baseline: 2.6297x; 2.1788x over previous
//
#include <hip/hip_runtime.h>

#define HW 64
#define NPIX 4096
#define NB 128
#define NA 10
#define HCH 150
#define VS 68      // LDS row stride (64 + 2 ring + pad)
#define VROWS 66

// workspace float offsets
#define R_OFF 0
#define R_SZ (NB * NPIX)        // 524288 floats
#define K5_OFF (R_SZ)           // 50 floats: K5[2][5][5]
#define C_OFF (K5_OFF + 50)     // 1
#define M_OFF (C_OFF + 1)       // 162: M[9][2][9]
#define BD_OFF (M_OFF + 162)    // 9
#define N_PRE 222

// ---------------------------------------------------------------------------
// Kernel 0: fold the 2->150->1 conv pair into composed 5x5 kernel + border
// correction kernels. One block (1 wave) per output element.
// ---------------------------------------------------------------------------
__global__ __launch_bounds__(64) void precompute_kernels(
        const float* __restrict__ Wh,   // [150][2][9]
        const float* __restrict__ bh,   // [150]
        const float* __restrict__ Wr,   // [150][9]
        float* __restrict__ ws) {
    int o = blockIdx.x;      // 0..221
    int lane = threadIdx.x;  // 0..63
    float s = 0.f;
    if (o < 50) {
        int ci = o / 25, uv = o % 25, u = uv / 5, v = uv % 5;
        for (int ch = lane; ch < HCH; ch += 64) {
            const float* wr = Wr + ch * 9;
            const float* wh = Wh + ch * 18 + ci * 9;
            for (int ky = 0; ky < 3; ++ky) {
                int ey = u - ky; if (ey < 0 || ey > 2) continue;
                for (int kx = 0; kx < 3; ++kx) {
                    int ex = v - kx; if (ex < 0 || ex > 2) continue;
                    s += wr[ky * 3 + kx] * wh[ey * 3 + ex];
                }
            }
        }
    } else if (o == 50) {
        for (int ch = lane; ch < HCH; ch += 64) {
            float wsum = 0.f;
            for (int t = 0; t < 9; ++t) wsum += Wr[ch * 9 + t];
            s += wsum * bh[ch];
        }
    } else if (o < 51 + 162) {
        int m = o - 51;
        int d = m / 18, rest = m % 18, ci = rest / 9, e = rest % 9;
        for (int ch = lane; ch < HCH; ch += 64)
            s += Wr[ch * 9 + d] * Wh[ch * 18 + ci * 9 + e];
    } else {
        int d = o - 213;
        for (int ch = lane; ch < HCH; ch += 64)
            s += Wr[ch * 9 + d] * bh[ch];
    }
    #pragma unroll
    for (int off = 32; off > 0; off >>= 1) s += __shfl_down(s, off);
    if (lane == 0) ws[K5_OFF + o] = s;
}

// ---------------------------------------------------------------------------
// Kernel 1: r = composed 5x5 conv on obs (+C), with exact border corrections.
// One thread per output pixel. (Round-0-proven version, unchanged.)
// ---------------------------------------------------------------------------
__global__ __launch_bounds__(256) void compute_r(
        const float* __restrict__ obs,    // [128][2][64][64]
        const float* __restrict__ wsro,   // K5/C/M/Bd region (ws base)
        float* __restrict__ rg) {         // [128][64][64]
    int idx = blockIdx.x * 256 + threadIdx.x;   // 0 .. 524287
    int b = idx >> 12, p = idx & 4095, y = p >> 6, x = p & 63;
    const float* ob0 = obs + (size_t)b * 2 * NPIX;
    const float* ob1 = ob0 + NPIX;
    const float* K5 = wsro + K5_OFF;
    float acc = wsro[C_OFF];
    #pragma unroll
    for (int u = 0; u < 5; ++u) {
        int gy = y + u - 2;
        if (gy < 0 || gy > 63) continue;
        #pragma unroll
        for (int v = 0; v < 5; ++v) {
            int gx = x + v - 2;
            if (gx < 0 || gx > 63) continue;
            acc += K5[u * 5 + v] * ob0[gy * 64 + gx]
                 + K5[25 + u * 5 + v] * ob1[gy * 64 + gx];
        }
    }
    if (y == 0 || y == 63 || x == 0 || x == 63) {
        const float* M  = wsro + M_OFF;
        const float* Bd = wsro + BD_OFF;
        for (int d = 0; d < 9; ++d) {
            int ny = y + d / 3 - 1, nx = x + d % 3 - 1;
            if (ny >= 0 && ny <= 63 && nx >= 0 && nx <= 63) continue;
            float corr = Bd[d];
            for (int e = 0; e < 9; ++e) {
                int oy = ny + e / 3 - 1, ox = nx + e % 3 - 1;
                if (oy < 0 || oy > 63 || ox < 0 || ox > 63) continue;
                corr += M[d * 18 + e]     * ob0[oy * 64 + ox]
                      + M[d * 18 + 9 + e] * ob1[oy * 64 + ox];
            }
            acc -= corr;
        }
    }
    rg[idx] = acc;
}

// ---------------------------------------------------------------------------
// Kernel 2: value iteration — round-0 kernel VERBATIM (the only spill-free
// configuration: 120 VGPR, 4 KB scratch, 141 us) plus ONE minimal addition:
// a tolerance-based early exit (contraction factor ~0.4 => max|dv| < 1e-7 by
// iter ~20; residual error < 2e-7 << 1.3e-3 threshold). Flags use a 2-slot
// ping-pong written/reset between the two EXISTING barriers — no new
// barriers, ~2 extra registers.
// ---------------------------------------------------------------------------
__global__ __launch_bounds__(512, 2) void vi_kernel(
        const float* __restrict__ rg,     // [128][64][64]
        const float* __restrict__ Wi,     // w_i2q [10][9]
        const float* __restrict__ Wvq,    // w_v2q [10][9]
        const float* __restrict__ Wfc,    // [8][10]
        const int* __restrict__ s1, const int* __restrict__ s2,
        const int* __restrict__ kptr,
        float* __restrict__ out) {        // [128][8]
    __shared__ float rlds[VROWS * VS];
    __shared__ float vlds[VROWS * VS];
    __shared__ float wil[90];
    __shared__ float wvl[90];
    __shared__ int   chg[2];
    int tid = threadIdx.x;
    int b = blockIdx.x;

    for (int i = tid; i < VROWS * VS; i += 512) { rlds[i] = 0.f; vlds[i] = 0.f; }
    if (tid < 90) { wil[tid] = Wi[tid]; wvl[tid] = Wvq[tid]; }
    if (tid < 2)  chg[tid] = 0;
    __syncthreads();

    const float* rb = rg + (size_t)b * NPIX;
    for (int i = tid; i < NPIX; i += 512) {
        int y = i >> 6, x = i & 63;
        rlds[(y + 1) * VS + (x + 1)] = rb[i];
    }
    __syncthreads();

    // thread owns a 4-row x 2-col patch
    int tx = tid & 31, ty = tid >> 5;
    int x0 = tx * 2, y0 = ty * 4;

    // qr[pixel][action] = conv(r, Wi) at pixel; v0 = max_a qr
    float qr[8][NA];
    #pragma unroll
    for (int py = 0; py < 4; ++py) {
        #pragma unroll
        for (int px = 0; px < 2; ++px) {
            int y = y0 + py, x = x0 + px;
            float rn[9];
            #pragma unroll
            for (int t = 0; t < 9; ++t)
                rn[t] = rlds[(y + t / 3) * VS + (x + t % 3)];
            float vmax = -1e30f;
            #pragma unroll
            for (int a = 0; a < NA; ++a) {
                float acc = 0.f;
                #pragma unroll
                for (int t = 0; t < 9; ++t) acc += wil[a * 9 + t] * rn[t];
                qr[py * 2 + px][a] = acc;
                vmax = fmaxf(vmax, acc);
            }
            vlds[(y + 1) * VS + (x + 1)] = vmax;
        }
    }

    // Wv into registers (round-0 pattern — compiler picks reg/LDS mix)
    float wv[NA][9];
    #pragma unroll
    for (int a = 0; a < NA; ++a)
        #pragma unroll
        for (int t = 0; t < 9; ++t) wv[a][t] = wvl[a * 9 + t];
    __syncthreads();

    int K = kptr[0];
    for (int it = 0; it < K; ++it) {
        // neighborhood of the 4x2 patch: 6 rows x 4 cols
        float vn[6][4];
        #pragma unroll
        for (int r = 0; r < 6; ++r)
            #pragma unroll
            for (int c = 0; c < 4; ++c)
                vn[r][c] = vlds[(y0 + r) * VS + (x0 + c)];
        float nv[8];
        bool changed = false;
        #pragma unroll
        for (int py = 0; py < 4; ++py) {
            #pragma unroll
            for (int px = 0; px < 2; ++px) {
                float m = -1e30f;
                #pragma unroll
                for (int a = 0; a < NA; ++a) {
                    float acc = qr[py * 2 + px][a];
                    #pragma unroll
                    for (int ky = 0; ky < 3; ++ky)
                        #pragma unroll
                        for (int kx = 0; kx < 3; ++kx)
                            acc += wv[a][ky * 3 + kx] * vn[py + ky][px + kx];
                    m = fmaxf(m, acc);
                }
                nv[py * 2 + px] = m;
                changed |= (fabsf(m - vn[py + 1][px + 1]) > 1e-7f);
            }
        }
        __syncthreads();   // B1: all reads of v_it done
        #pragma unroll
        for (int py = 0; py < 4; ++py)
            #pragma unroll
            for (int px = 0; px < 2; ++px)
                vlds[(y0 + py + 1) * VS + (x0 + px + 1)] = nv[py * 2 + px];
        chg[(it + 1) & 1] = 0;          // reset next slot: its "=1" writers run
                                        // after B1(it+1) > B2(it) > this write
        if (changed) chg[it & 1] = 1;   // benign same-value race
        __syncthreads();   // B2: v_{it+1} + flags visible
        if (chg[it & 1] == 0) break;    // converged: |dv| < 1e-7 everywhere;
                                        // residual < 2e-7 << 1.3e-3 threshold
    }

    // final q at attended pixel + FC (round-0 tail: all from LDS, tid 0)
    if (tid == 0) {
        int yy = s1[b], xx = s2[b];
        float q[NA];
        #pragma unroll
        for (int a = 0; a < NA; ++a) {
            float acc = 0.f;
            for (int t = 0; t < 9; ++t) {
                int ly = yy + t / 3, lx = xx + t % 3;
                acc += wil[a * 9 + t] * rlds[ly * VS + lx]
                     + wvl[a * 9 + t] * vlds[ly * VS + lx];
            }
            q[a] = acc;
        }
        for (int n = 0; n < 8; ++n) {
            float o = 0.f;
            for (int a = 0; a < NA; ++a) o += q[a] * Wfc[n * NA + a];
            out[b * 8 + n] = o;
        }
    }
}

// ---------------------------------------------------------------------------
extern "C" void kernel_launch(void* const* d_in, const int* in_sizes, int n_in,
                              void* d_out, int out_size, void* d_ws, size_t ws_size,
                              hipStream_t stream) {
    const int*   s1   = (const int*)d_in[0];
    const int*   s2   = (const int*)d_in[1];
    const float* obs  = (const float*)d_in[2];
    const int*   kptr = (const int*)d_in[3];
    const float* Wh   = (const float*)d_in[4];
    const float* bh   = (const float*)d_in[5];
    const float* Wr   = (const float*)d_in[6];
    const float* Wi   = (const float*)d_in[7];
    const float* Wvq  = (const float*)d_in[8];
    const float* Wfc  = (const float*)d_in[9];
    float* out = (float*)d_out;
    float* ws  = (float*)d_ws;

    precompute_kernels<<<N_PRE, 64, 0, stream>>>(Wh, bh, Wr, ws);
    compute_r<<<2048, 256, 0, stream>>>(obs, ws, ws + R_OFF);
    vi_kernel<<<NB, 512, 0, stream>>>(ws + R_OFF, Wi, Wvq, Wfc, s1, s2, kptr, out);
}